// Round 5
// baseline (111.388 us; speedup 1.0000x reference)
//
#include <hip/hip_runtime.h>

#define CLIP 4096
#define H1   2048
#define H2   1024
#define RN   4096
#define H_STEP 2.44140625f   // r_i = H_STEP*(i+1) exactly
#define G1   32768           // Sturm grid points per l (65536 chains = 1024 SIMDs x 64 lanes)

// ---- monotone float<->uint map for atomic min/max of floats -----------------
__device__ __forceinline__ unsigned fmap(float f) {
    unsigned u = __float_as_uint(f);
    return (u & 0x80000000u) ? ~u : (u | 0x80000000u);
}
__device__ __forceinline__ float funmap(unsigned u) {
    return __uint_as_float((u & 0x80000000u) ? (u & 0x7fffffffu) : ~u);
}
__device__ __forceinline__ void spect_bounds(const unsigned* bu, float& lo, float& cell) {
    float mn = funmap(bu[0]), mx = funmap(bu[1]);
    lo = mn - 1e-3f;                              // Gershgorin: lambda_min >= min ptl
    float hi = mx + 2.33554432f + 1e-3f;          // lambda_max <= max ptl + 2 + 2/r0^2
    cell = (hi - lo) * (1.0f / (float)G1);
}

// ---------------- Layer 1 split-K partials: partA[c][j] ----------------------
__global__ __launch_bounds__(256) void part1(const float* __restrict__ W,
                                             const float* __restrict__ x,
                                             float* __restrict__ partA,
                                             unsigned* __restrict__ bu) {
    if (blockIdx.x == 0 && blockIdx.y == 0 && threadIdx.x == 0) {
        bu[0] = 0xFFFFFFFFu;   // running min (mapped)
        bu[1] = 0u;            // running max (mapped)
    }
    int j = blockIdx.x * 256 + threadIdx.x;       // 8 x-blocks -> j < 2048
    int i0 = blockIdx.y * 64;                     // 64 k-chunks of 64 rows
    const float* Wp = W + (size_t)i0 * H1 + j;
    float acc = 0.f;
#pragma unroll 8
    for (int i = 0; i < 64; ++i)
        acc = fmaf(x[i0 + i], Wp[(size_t)i * H1], acc);   // x uniform -> s_load
    partA[(size_t)blockIdx.y * H1 + j] = acc;
}

// ------- Layer 2, fused: prologue reduces the 16 h1 values this block needs --
__global__ __launch_bounds__(256) void part2f(const float* __restrict__ W,
                                              const float* __restrict__ partA,
                                              const float* __restrict__ b,
                                              float* __restrict__ partB) {
    __shared__ float xs[16];
    int t = threadIdx.x;
    int i_loc = t >> 4, c_loc = t & 15;           // 16 i's x 16 lanes
    int i0 = blockIdx.y * 16;                     // 128 k-chunks of 16 rows
    float s = 0.f;
#pragma unroll
    for (int k = 0; k < 4; ++k)                   // 64 layer-1 partials
        s += partA[(size_t)(c_loc + 16 * k) * H1 + i0 + i_loc];
    s += __shfl_xor(s, 1); s += __shfl_xor(s, 2);
    s += __shfl_xor(s, 4); s += __shfl_xor(s, 8);
    if (c_loc == 0) xs[i_loc] = fmaxf(s + b[i0 + i_loc], 0.f);
    __syncthreads();
    float xv[16];
#pragma unroll
    for (int u = 0; u < 16; ++u) xv[u] = xs[u];
    int j = blockIdx.x * 256 + t;                 // 4 x-blocks -> j < 1024
    const float* Wp = W + (size_t)i0 * H2 + j;
    float acc = 0.f;
#pragma unroll
    for (int i = 0; i < 16; ++i)
        acc = fmaf(xv[i], Wp[(size_t)i * H2], acc);
    partB[(size_t)blockIdx.y * H2 + j] = acc;
}

// ------- Layer 3, fused: prologue reduces the 32 h2 values this block needs --
__global__ __launch_bounds__(256) void part3f(const float* __restrict__ W,
                                              const float* __restrict__ partB,
                                              const float* __restrict__ b,
                                              float* __restrict__ partA) {
    __shared__ float xs[32];
    int t = threadIdx.x;
    int i_loc = t >> 3, c_loc = t & 7;            // 32 i's x 8 lanes
    int i0 = blockIdx.y * 32;                     // 32 k-chunks of 32 rows
    float s = 0.f;
#pragma unroll
    for (int k = 0; k < 16; ++k)                  // 128 layer-2 partials
        s += partB[(size_t)(c_loc + 8 * k) * H2 + i0 + i_loc];
    s += __shfl_xor(s, 1); s += __shfl_xor(s, 2); s += __shfl_xor(s, 4);
    if (c_loc == 0) xs[i_loc] = fmaxf(s + b[i0 + i_loc], 0.f);
    __syncthreads();
    float xv[32];
#pragma unroll
    for (int u = 0; u < 32; ++u) xv[u] = xs[u];
    int j = blockIdx.x * 256 + t;                 // 16 x-blocks -> j < 4096
    const float* Wp = W + (size_t)i0 * RN + j;
    float acc = 0.f;
#pragma unroll
    for (int i = 0; i < 32; ++i)
        acc = fmaf(xv[i], Wp[(size_t)i * RN], acc);
    partA[(size_t)blockIdx.y * RN + j] = acc;
}

// ---- Final fin: ptl -> d_out, D0/D1 = 2*diag (contiguous), spectral bounds --
__global__ __launch_bounds__(256) void fin3(const float* __restrict__ partA,
                                            const float* __restrict__ b,
                                            float* __restrict__ out,
                                            float* __restrict__ D,
                                            unsigned* __restrict__ bu) {
    __shared__ float smn[4], smx[4];
    int j = blockIdx.x * 256 + threadIdx.x;
    float s = b[j];
#pragma unroll 8
    for (int c = 0; c < 32; ++c) s += partA[(size_t)c * RN + j];
    out[j] = s;                                   // ptl -> d_out[0:RN]
    float r = H_STEP * (float)(j + 1);
    float base = 2.0f + 2.0f * s;                 // 2*(1 + ptl)
    D[j] = base;                                  // l = 0
    D[RN + j] = base + 4.0f / (r * r);            // l = 1: + 2*l(l+1)/r^2
    float mn = s, mx = s;
    for (int off = 32; off; off >>= 1) {
        mn = fminf(mn, __shfl_down(mn, off));
        mx = fmaxf(mx, __shfl_down(mx, off));
    }
    int tid = threadIdx.x;
    if ((tid & 63) == 0) { smn[tid >> 6] = mn; smx[tid >> 6] = mx; }
    __syncthreads();
    if (tid == 0) {
        for (int w = 1; w < 4; ++w) { mn = fminf(mn, smn[w]); mx = fmaxf(mx, smx[w]); }
        atomicMin(&bu[0], fmap(mn));
        atomicMax(&bu[1], fmap(mx));
    }
}

// -------- Sturm count, f32 char-poly recurrence  q_i = (D_i - X) q_{i-1} - q_{i-2}
// D = 2*diag, X = 2*x kills the 0.25 coefficient -> one fma per step.
// d values are wave-uniform -> read via the SCALAR pipe (s_load), no LDS:
// 32-value register double-buffer hides SMEM latency under ~350 cyc of VALU.
#define STEP(dv)                                                           \
    {                                                                      \
        float t = (dv) - X;                                                \
        float p = fmaf(t, pm1, -pm2);                                      \
        cnt += (__float_as_uint(p) ^ __float_as_uint(pm1)) >> 31;          \
        pm2 = pm1; pm1 = p;                                                \
    }

__global__ __launch_bounds__(256) void stage1(const float* __restrict__ Dall,
                                              const unsigned* __restrict__ bu,
                                              int* __restrict__ counts) {
    const float* __restrict__ Dp = Dall + (blockIdx.y << 12);   // D0 | D1
    float lo, cell;
    spect_bounds(bu, lo, cell);
    int j = blockIdx.x * 256 + threadIdx.x;
    float X = 2.0f * (lo + cell * (float)j);

    float pm1 = 1.0f, pm2 = 0.0f;
    unsigned cnt = 0;
    float nb[32];
#pragma unroll
    for (int u = 0; u < 32; ++u) nb[u] = Dp[u];   // uniform -> scalar loads
    for (int w = 0; w < RN / 32; ++w) {
        float cb[32];
#pragma unroll
        for (int u = 0; u < 32; ++u) cb[u] = nb[u];
        if (w + 1 < RN / 32) {
            const float* q = Dp + (w + 1) * 32;
#pragma unroll
            for (int u = 0; u < 32; ++u) nb[u] = q[u];   // prefetch next batch
        }
#pragma unroll
        for (int h = 0; h < 2; ++h) {
#pragma unroll
            for (int u = 0; u < 16; ++u) STEP(cb[h * 16 + u])
            // renormalize: bring max(|pm1|,|pm2|) exponent back to ~2^0.
            // |t| <= ~25 -> growth/decay over 16 steps <= 2^~75: no clamp needed.
            unsigned a1 = __float_as_uint(pm1) & 0x7fffffffu;
            unsigned a2 = __float_as_uint(pm2) & 0x7fffffffu;
            unsigned hm = a1 > a2 ? a1 : a2;
            int es = 254 - (int)(hm >> 23);
            es = es < 1 ? 1 : es;
            float sc = __uint_as_float((unsigned)es << 23);
            pm1 *= sc; pm2 *= sc;
        }
    }
    counts[(blockIdx.y << 15) + j] = (int)cnt;
}

// ------------- final: bracket search (noise-tolerant) + midpoint -------------
__global__ __launch_bounds__(256) void final_eig(const int* __restrict__ counts,
                                                 const unsigned* __restrict__ bu,
                                                 float* __restrict__ out) {
    int e = blockIdx.x * 256 + threadIdx.x;       // 8192 eigenvalues (l,k)
    int l = e >> 12, k = e & (RN - 1);
    const int* c = counts + (l << 15);
    int lo_i = 0, hi_i = G1 - 1;                  // last j with c[j] <= k
    while (lo_i < hi_i) {
        int mid = (lo_i + hi_i + 1) >> 1;
        if (c[mid] <= k) lo_i = mid; else hi_i = mid - 1;
    }
    while (lo_i > 0 && c[lo_i] > k) --lo_i;       // +-1 noise fixups
    while (lo_i < G1 - 1 && c[lo_i + 1] <= k) ++lo_i;
    float lo, cell;
    spect_bounds(bu, lo, cell);
    out[e] = lo + cell * ((float)lo_i + 0.5f);
}

extern "C" void kernel_launch(void* const* d_in, const int* in_sizes, int n_in,
                              void* d_out, int out_size, void* d_ws, size_t ws_size,
                              hipStream_t stream) {
    const float* energy = (const float*)d_in[0];
    const float* W1 = (const float*)d_in[1];
    const float* b1 = (const float*)d_in[2];
    const float* W2 = (const float*)d_in[3];
    const float* b2 = (const float*)d_in[4];
    const float* W3 = (const float*)d_in[5];
    const float* b3 = (const float*)d_in[6];
    float* out = (float*)d_out;                   // [RN] ptl, then [2*RN] eigenvalues

    float* ws = (float*)d_ws;
    float*    partA  = ws;                        // 131072 f32 (layers 1,3)
    float*    partB  = partA + 131072;            // 131072 f32 (layer 2)
    float*    D      = partB + 131072;            // 2*RN f32 (D0 | D1)
    unsigned* bu     = (unsigned*)(D + 2 * RN);   // 2 u32
    int*      counts = (int*)(bu + 4);            // 2*G1 i32

    // ---- MLP: 3 GEMVs, fins fused into next layer's prologue (6 kernels) ----
    part1 <<<dim3(8, 64),  256, 0, stream>>>(W1, energy, partA, bu);
    part2f<<<dim3(4, 128), 256, 0, stream>>>(W2, partA, b1, partB);
    part3f<<<dim3(16, 32), 256, 0, stream>>>(W3, partB, b2, partA);
    fin3  <<<RN / 256,     256, 0, stream>>>(partA, b3, out, D, bu);

    // ---- Eigenvalues: single-stage f32 Sturm multisection ----
    stage1<<<dim3(G1 / 256, 2), 256, 0, stream>>>(D, bu, counts);
    final_eig<<<2 * RN / 256, 256, 0, stream>>>(counts, bu, out + RN);
}

// Round 6
// 90.173 us; speedup vs baseline: 1.2353x; 1.2353x over previous
//
#include <hip/hip_runtime.h>

#define CLIP 4096
#define H1   2048
#define H2   1024
#define RN   4096
#define H_STEP 2.44140625f   // r_i = H_STEP*(i+1) exactly
#define G1   65536           // Sturm grid points per l (131072 chains = 2 waves/SIMD)

// ---- monotone float<->uint map for atomic min/max of floats -----------------
__device__ __forceinline__ unsigned fmap(float f) {
    unsigned u = __float_as_uint(f);
    return (u & 0x80000000u) ? ~u : (u | 0x80000000u);
}
__device__ __forceinline__ float funmap(unsigned u) {
    return __uint_as_float((u & 0x80000000u) ? (u & 0x7fffffffu) : ~u);
}
__device__ __forceinline__ void spect_bounds(const unsigned* bu, float& lo, float& cell) {
    float mn = funmap(bu[0]), mx = funmap(bu[1]);
    lo = mn - 1e-3f;                              // Gershgorin: lambda_min >= min ptl
    float hi = mx + 2.33554432f + 1e-3f;          // lambda_max <= max ptl + 2 + 2/r0^2
    cell = (hi - lo) * (1.0f / (float)G1);
}

// ---------------- Layer 1 split-K partials: partA[c][j] ----------------------
__global__ __launch_bounds__(256) void part1(const float* __restrict__ W,
                                             const float* __restrict__ x,
                                             float* __restrict__ partA,
                                             unsigned* __restrict__ bu) {
    if (blockIdx.x == 0 && blockIdx.y == 0 && threadIdx.x == 0) {
        bu[0] = 0xFFFFFFFFu;   // running min (mapped)
        bu[1] = 0u;            // running max (mapped)
    }
    int j = blockIdx.x * 256 + threadIdx.x;       // 8 x-blocks -> j < 2048
    int i0 = blockIdx.y * 64;                     // 64 k-chunks of 64 rows
    const float* Wp = W + (size_t)i0 * H1 + j;
    float acc = 0.f;
#pragma unroll 8
    for (int i = 0; i < 64; ++i)
        acc = fmaf(x[i0 + i], Wp[(size_t)i * H1], acc);   // x uniform -> s_load
    partA[(size_t)blockIdx.y * H1 + j] = acc;
}

// ------- Layer 2, fused: prologue reduces the 16 h1 values this block needs --
__global__ __launch_bounds__(256) void part2f(const float* __restrict__ W,
                                              const float* __restrict__ partA,
                                              const float* __restrict__ b,
                                              float* __restrict__ partB) {
    __shared__ float xs[16];
    int t = threadIdx.x;
    int i_loc = t >> 4, c_loc = t & 15;           // 16 i's x 16 lanes
    int i0 = blockIdx.y * 16;                     // 128 k-chunks of 16 rows
    float s = 0.f;
#pragma unroll
    for (int k = 0; k < 4; ++k)                   // 64 layer-1 partials
        s += partA[(size_t)(c_loc + 16 * k) * H1 + i0 + i_loc];
    s += __shfl_xor(s, 1); s += __shfl_xor(s, 2);
    s += __shfl_xor(s, 4); s += __shfl_xor(s, 8);
    if (c_loc == 0) xs[i_loc] = fmaxf(s + b[i0 + i_loc], 0.f);
    __syncthreads();
    float xv[16];
#pragma unroll
    for (int u = 0; u < 16; ++u) xv[u] = xs[u];
    int j = blockIdx.x * 256 + t;                 // 4 x-blocks -> j < 1024
    const float* Wp = W + (size_t)i0 * H2 + j;
    float acc = 0.f;
#pragma unroll
    for (int i = 0; i < 16; ++i)
        acc = fmaf(xv[i], Wp[(size_t)i * H2], acc);
    partB[(size_t)blockIdx.y * H2 + j] = acc;
}

// ------- Layer 3, fused: prologue reduces the 32 h2 values this block needs --
__global__ __launch_bounds__(256) void part3f(const float* __restrict__ W,
                                              const float* __restrict__ partB,
                                              const float* __restrict__ b,
                                              float* __restrict__ partA) {
    __shared__ float xs[32];
    int t = threadIdx.x;
    int i_loc = t >> 3, c_loc = t & 7;            // 32 i's x 8 lanes
    int i0 = blockIdx.y * 32;                     // 32 k-chunks of 32 rows
    float s = 0.f;
#pragma unroll
    for (int k = 0; k < 16; ++k)                  // 128 layer-2 partials
        s += partB[(size_t)(c_loc + 8 * k) * H2 + i0 + i_loc];
    s += __shfl_xor(s, 1); s += __shfl_xor(s, 2); s += __shfl_xor(s, 4);
    if (c_loc == 0) xs[i_loc] = fmaxf(s + b[i0 + i_loc], 0.f);
    __syncthreads();
    float xv[32];
#pragma unroll
    for (int u = 0; u < 32; ++u) xv[u] = xs[u];
    int j = blockIdx.x * 256 + t;                 // 16 x-blocks -> j < 4096
    const float* Wp = W + (size_t)i0 * RN + j;
    float acc = 0.f;
#pragma unroll
    for (int i = 0; i < 32; ++i)
        acc = fmaf(xv[i], Wp[(size_t)i * RN], acc);
    partA[(size_t)blockIdx.y * RN + j] = acc;
}

// ---- Final fin: ptl -> d_out, D0/D1 = 2*diag (contiguous), spectral bounds --
__global__ __launch_bounds__(256) void fin3(const float* __restrict__ partA,
                                            const float* __restrict__ b,
                                            float* __restrict__ out,
                                            float* __restrict__ D,
                                            unsigned* __restrict__ bu) {
    __shared__ float smn[4], smx[4];
    int j = blockIdx.x * 256 + threadIdx.x;
    float s = b[j];
#pragma unroll 8
    for (int c = 0; c < 32; ++c) s += partA[(size_t)c * RN + j];
    out[j] = s;                                   // ptl -> d_out[0:RN]
    float r = H_STEP * (float)(j + 1);
    float base = 2.0f + 2.0f * s;                 // 2*(1 + ptl)
    D[j] = base;                                  // l = 0
    D[RN + j] = base + 4.0f / (r * r);            // l = 1: + 2*l(l+1)/r^2
    float mn = s, mx = s;
    for (int off = 32; off; off >>= 1) {
        mn = fminf(mn, __shfl_down(mn, off));
        mx = fmaxf(mx, __shfl_down(mx, off));
    }
    int tid = threadIdx.x;
    if ((tid & 63) == 0) { smn[tid >> 6] = mn; smx[tid >> 6] = mx; }
    __syncthreads();
    if (tid == 0) {
        for (int w = 1; w < 4; ++w) { mn = fminf(mn, smn[w]); mx = fmaxf(mx, smx[w]); }
        atomicMin(&bu[0], fmap(mn));
        atomicMax(&bu[1], fmap(mx));
    }
}

// -------- Sturm count, f32 char-poly recurrence  q_i = (D_i - X) q_{i-1} - q_{i-2}
// D = 2*diag, X = 2*x kills the 0.25 coefficient -> one fma per step.
// G1=65536 -> 512 blocks -> 2 waves/SIMD: TLP hides fma-chain + LDS latency.
// LDS float4 stream with 2-ahead register prefetch covers ds_read latency
// even within a single wave.
#define STEP(dv)                                                           \
    {                                                                      \
        float t = (dv) - X;                                                \
        float p = fmaf(t, pm1, -pm2);                                      \
        cnt += (__float_as_uint(p) ^ __float_as_uint(pm1)) >> 31;          \
        pm2 = pm1; pm1 = p;                                                \
    }

__global__ __launch_bounds__(256) void stage1(const float* __restrict__ Dall,
                                              const unsigned* __restrict__ bu,
                                              int* __restrict__ counts) {
    __shared__ alignas(16) float ds[RN];
    const float* Dsrc = Dall + (blockIdx.y << 12);   // D0 | D1
    for (int i = threadIdx.x; i < RN / 4; i += 256)
        reinterpret_cast<float4*>(ds)[i] = reinterpret_cast<const float4*>(Dsrc)[i];
    __syncthreads();

    float lo, cell;
    spect_bounds(bu, lo, cell);
    int j = blockIdx.x * 256 + threadIdx.x;          // 256 x-blocks -> j < 65536
    float X = 2.0f * (lo + cell * (float)j);

    float pm1 = 1.0f, pm2 = 0.0f;
    unsigned cnt = 0;
    const float4* d4 = reinterpret_cast<const float4*>(ds);
    float4 buf0 = d4[0], buf1 = d4[1];
#pragma unroll 4
    for (int w = 0; w < RN / 4; ++w) {               // 1024 iters, 4 steps each
        float4 cur = buf0;
        buf0 = buf1;
        buf1 = d4[(w + 2) & (RN / 4 - 1)];           // 2-ahead prefetch (wraps, unused)
        STEP(cur.x) STEP(cur.y) STEP(cur.z) STEP(cur.w)
        if ((w & 3) == 3) {
            // renormalize every 16 steps: bring max exponent back to ~2^0.
            // |t| <= ~30 -> growth <= 2^79 per 16 steps: safe within f32.
            unsigned a1 = __float_as_uint(pm1) & 0x7fffffffu;
            unsigned a2 = __float_as_uint(pm2) & 0x7fffffffu;
            unsigned hm = a1 > a2 ? a1 : a2;
            int es = 254 - (int)(hm >> 23);
            es = es < 1 ? 1 : es;
            float sc = __uint_as_float((unsigned)es << 23);
            pm1 *= sc; pm2 *= sc;
        }
    }
    counts[(blockIdx.y << 16) + j] = (int)cnt;
}

// ------------- final: bracket search (noise-tolerant) + midpoint -------------
__global__ __launch_bounds__(256) void final_eig(const int* __restrict__ counts,
                                                 const unsigned* __restrict__ bu,
                                                 float* __restrict__ out) {
    int e = blockIdx.x * 256 + threadIdx.x;       // 8192 eigenvalues (l,k)
    int l = e >> 12, k = e & (RN - 1);
    const int* c = counts + (l << 16);
    int lo_i = 0, hi_i = G1 - 1;                  // last j with c[j] <= k
    while (lo_i < hi_i) {
        int mid = (lo_i + hi_i + 1) >> 1;
        if (c[mid] <= k) lo_i = mid; else hi_i = mid - 1;
    }
    while (lo_i > 0 && c[lo_i] > k) --lo_i;       // +-1 noise fixups
    while (lo_i < G1 - 1 && c[lo_i + 1] <= k) ++lo_i;
    float lo, cell;
    spect_bounds(bu, lo, cell);
    out[e] = lo + cell * ((float)lo_i + 0.5f);
}

extern "C" void kernel_launch(void* const* d_in, const int* in_sizes, int n_in,
                              void* d_out, int out_size, void* d_ws, size_t ws_size,
                              hipStream_t stream) {
    const float* energy = (const float*)d_in[0];
    const float* W1 = (const float*)d_in[1];
    const float* b1 = (const float*)d_in[2];
    const float* W2 = (const float*)d_in[3];
    const float* b2 = (const float*)d_in[4];
    const float* W3 = (const float*)d_in[5];
    const float* b3 = (const float*)d_in[6];
    float* out = (float*)d_out;                   // [RN] ptl, then [2*RN] eigenvalues

    float* ws = (float*)d_ws;
    float*    partA  = ws;                        // 131072 f32 (layers 1,3)
    float*    partB  = partA + 131072;            // 131072 f32 (layer 2)
    float*    D      = partB + 131072;            // 2*RN f32 (D0 | D1)
    unsigned* bu     = (unsigned*)(D + 2 * RN);   // 2 u32
    int*      counts = (int*)(bu + 4);            // 2*G1 i32 (512 KB)

    // ---- MLP: 3 GEMVs, fins fused into next layer's prologue ----
    part1 <<<dim3(8, 64),  256, 0, stream>>>(W1, energy, partA, bu);
    part2f<<<dim3(4, 128), 256, 0, stream>>>(W2, partA, b1, partB);
    part3f<<<dim3(16, 32), 256, 0, stream>>>(W3, partB, b2, partA);
    fin3  <<<RN / 256,     256, 0, stream>>>(partA, b3, out, D, bu);

    // ---- Eigenvalues: single-stage f32 Sturm multisection, 2 waves/SIMD ----
    stage1<<<dim3(G1 / 256, 2), 256, 0, stream>>>(D, bu, counts);
    final_eig<<<2 * RN / 256, 256, 0, stream>>>(counts, bu, out + RN);
}

// Round 7
// 87.185 us; speedup vs baseline: 1.2776x; 1.0343x over previous
//
#include <hip/hip_runtime.h>

#define CLIP 4096
#define H1   2048
#define H2   1024
#define RN   4096
#define H_STEP 2.44140625f   // r_i = H_STEP*(i+1) exactly
#define G1   65536           // Sturm grid points per l (131072 chains = 2 waves/SIMD)

// ---- monotone float<->uint map for atomic min/max of floats -----------------
__device__ __forceinline__ unsigned fmap(float f) {
    unsigned u = __float_as_uint(f);
    return (u & 0x80000000u) ? ~u : (u | 0x80000000u);
}
__device__ __forceinline__ float funmap(unsigned u) {
    return __uint_as_float((u & 0x80000000u) ? (u & 0x7fffffffu) : ~u);
}
__device__ __forceinline__ void spect_bounds(const unsigned* bu, float& lo, float& cell) {
    float mn = funmap(bu[0]), mx = funmap(bu[1]);
    lo = mn - 1e-3f;                              // Gershgorin: lambda_min >= min ptl
    float hi = mx + 2.33554432f + 1e-3f;          // lambda_max <= max ptl + 2 + 2/r0^2
    cell = (hi - lo) * (1.0f / (float)G1);
}

// ---------------- Layer 1 split-K partials: partA[c][j] ----------------------
__global__ __launch_bounds__(256) void part1(const float* __restrict__ W,
                                             const float* __restrict__ x,
                                             float* __restrict__ partA,
                                             unsigned* __restrict__ bu) {
    if (blockIdx.x == 0 && blockIdx.y == 0 && threadIdx.x == 0) {
        bu[0] = 0xFFFFFFFFu;   // running min (mapped)
        bu[1] = 0u;            // running max (mapped)
    }
    int j = blockIdx.x * 256 + threadIdx.x;       // 8 x-blocks -> j < 2048
    int i0 = blockIdx.y * 64;                     // 64 k-chunks of 64 rows
    const float* Wp = W + (size_t)i0 * H1 + j;
    float acc = 0.f;
#pragma unroll 8
    for (int i = 0; i < 64; ++i)
        acc = fmaf(x[i0 + i], Wp[(size_t)i * H1], acc);   // x uniform -> s_load
    partA[(size_t)blockIdx.y * H1 + j] = acc;
}

// ------- Layer 2, fused: prologue reduces the 16 h1 values this block needs --
__global__ __launch_bounds__(256) void part2f(const float* __restrict__ W,
                                              const float* __restrict__ partA,
                                              const float* __restrict__ b,
                                              float* __restrict__ partB) {
    __shared__ float xs[16];
    int t = threadIdx.x;
    int i_loc = t >> 4, c_loc = t & 15;           // 16 i's x 16 lanes
    int i0 = blockIdx.y * 16;                     // 128 k-chunks of 16 rows
    float s = 0.f;
#pragma unroll
    for (int k = 0; k < 4; ++k)                   // 64 layer-1 partials
        s += partA[(size_t)(c_loc + 16 * k) * H1 + i0 + i_loc];
    s += __shfl_xor(s, 1); s += __shfl_xor(s, 2);
    s += __shfl_xor(s, 4); s += __shfl_xor(s, 8);
    if (c_loc == 0) xs[i_loc] = fmaxf(s + b[i0 + i_loc], 0.f);
    __syncthreads();
    float xv[16];
#pragma unroll
    for (int u = 0; u < 16; ++u) xv[u] = xs[u];
    int j = blockIdx.x * 256 + t;                 // 4 x-blocks -> j < 1024
    const float* Wp = W + (size_t)i0 * H2 + j;
    float acc = 0.f;
#pragma unroll
    for (int i = 0; i < 16; ++i)
        acc = fmaf(xv[i], Wp[(size_t)i * H2], acc);
    partB[(size_t)blockIdx.y * H2 + j] = acc;
}

// ------- Layer 3, fused: prologue reduces the 32 h2 values this block needs --
__global__ __launch_bounds__(256) void part3f(const float* __restrict__ W,
                                              const float* __restrict__ partB,
                                              const float* __restrict__ b,
                                              float* __restrict__ partA) {
    __shared__ float xs[32];
    int t = threadIdx.x;
    int i_loc = t >> 3, c_loc = t & 7;            // 32 i's x 8 lanes
    int i0 = blockIdx.y * 32;                     // 32 k-chunks of 32 rows
    float s = 0.f;
#pragma unroll
    for (int k = 0; k < 16; ++k)                  // 128 layer-2 partials
        s += partB[(size_t)(c_loc + 8 * k) * H2 + i0 + i_loc];
    s += __shfl_xor(s, 1); s += __shfl_xor(s, 2); s += __shfl_xor(s, 4);
    if (c_loc == 0) xs[i_loc] = fmaxf(s + b[i0 + i_loc], 0.f);
    __syncthreads();
    float xv[32];
#pragma unroll
    for (int u = 0; u < 32; ++u) xv[u] = xs[u];
    int j = blockIdx.x * 256 + t;                 // 16 x-blocks -> j < 4096
    const float* Wp = W + (size_t)i0 * RN + j;
    float acc = 0.f;
#pragma unroll
    for (int i = 0; i < 32; ++i)
        acc = fmaf(xv[i], Wp[(size_t)i * RN], acc);
    partA[(size_t)blockIdx.y * RN + j] = acc;
}

// ---- Final fin: ptl -> d_out, D0/D1 = 2*diag (contiguous), spectral bounds --
__global__ __launch_bounds__(256) void fin3(const float* __restrict__ partA,
                                            const float* __restrict__ b,
                                            float* __restrict__ out,
                                            float* __restrict__ D,
                                            unsigned* __restrict__ bu) {
    __shared__ float smn[4], smx[4];
    int j = blockIdx.x * 256 + threadIdx.x;
    float s = b[j];
#pragma unroll 8
    for (int c = 0; c < 32; ++c) s += partA[(size_t)c * RN + j];
    out[j] = s;                                   // ptl -> d_out[0:RN]
    float r = H_STEP * (float)(j + 1);
    float base = 2.0f + 2.0f * s;                 // 2*(1 + ptl)
    D[j] = base;                                  // l = 0
    D[RN + j] = base + 4.0f / (r * r);            // l = 1: + 2*l(l+1)/r^2
    float mn = s, mx = s;
    for (int off = 32; off; off >>= 1) {
        mn = fminf(mn, __shfl_down(mn, off));
        mx = fmaxf(mx, __shfl_down(mx, off));
    }
    int tid = threadIdx.x;
    if ((tid & 63) == 0) { smn[tid >> 6] = mn; smx[tid >> 6] = mx; }
    __syncthreads();
    if (tid == 0) {
        for (int w = 1; w < 4; ++w) { mn = fminf(mn, smn[w]); mx = fmaxf(mx, smx[w]); }
        atomicMin(&bu[0], fmap(mn));
        atomicMax(&bu[1], fmap(mx));
    }
}

// -------- Sturm count, f32 char-poly recurrence  q_i = (D_i - X) q_{i-1} - q_{i-2}
// D = 2*diag, X = 2*x kills the 0.25 coefficient -> one fma per step.
// Per-step cost target 4 VALU: v_sub, v_fma, v_lshrrev (sign), v_xad (count).
// 16-step unroll (register ping-pong at group level) removes all movs;
// renorm every 16 steps (growth/decay bounded by ~2^59, safe in f32).
#define STEP(dv)                                                           \
    {                                                                      \
        float t = (dv) - X;                                                \
        float p = fmaf(t, pm1, -pm2);                                      \
        unsigned sg = __float_as_uint(p) >> 31;                            \
        cnt += (sg ^ sp);      /* xor+add -> v_xad_u32 */                  \
        sp = sg; pm2 = pm1; pm1 = p;                                       \
    }

#define RENORM                                                             \
    {                                                                      \
        unsigned a1 = __float_as_uint(pm1) & 0x7fffffffu;                  \
        unsigned a2 = __float_as_uint(pm2) & 0x7fffffffu;                  \
        unsigned hm = a1 > a2 ? a1 : a2;                                   \
        int es = 254 - (int)(hm >> 23);                                    \
        es = es < 1 ? 1 : es;                                              \
        float sc = __uint_as_float((unsigned)es << 23);                    \
        pm1 *= sc; pm2 *= sc;                                              \
    }

#define GRP(v0, v1, v2, v3)                                                \
    {                                                                      \
        STEP(v0.x) STEP(v0.y) STEP(v0.z) STEP(v0.w)                        \
        STEP(v1.x) STEP(v1.y) STEP(v1.z) STEP(v1.w)                        \
        STEP(v2.x) STEP(v2.y) STEP(v2.z) STEP(v2.w)                        \
        STEP(v3.x) STEP(v3.y) STEP(v3.z) STEP(v3.w)                        \
        RENORM                                                             \
    }

__global__ __launch_bounds__(256) void stage1(const float* __restrict__ Dall,
                                              const unsigned* __restrict__ bu,
                                              int* __restrict__ counts) {
    __shared__ alignas(16) float ds[RN];
    const float* Dsrc = Dall + (blockIdx.y << 12);   // D0 | D1
    for (int i = threadIdx.x; i < RN / 4; i += 256)
        reinterpret_cast<float4*>(ds)[i] = reinterpret_cast<const float4*>(Dsrc)[i];
    __syncthreads();

    float lo, cell;
    spect_bounds(bu, lo, cell);
    int j = blockIdx.x * 256 + threadIdx.x;          // 256 x-blocks -> j < 65536
    float X = 2.0f * (lo + cell * (float)j);

    float pm1 = 1.0f, pm2 = 0.0f;
    unsigned cnt = 0, sp = 0;
    const float4* d4 = reinterpret_cast<const float4*>(ds);

    // group = 16 steps = 4 float4s; ping-pong A/B register sets: load next
    // group while computing current (no per-step copies).
    float4 A0 = d4[0], A1 = d4[1], A2 = d4[2], A3 = d4[3];
    float4 B0, B1, B2, B3;
    for (int g = 0; g < 256; g += 2) {               // 256 groups of 16 steps
        int nb = ((g + 1) & 255) << 2;
        B0 = d4[nb]; B1 = d4[nb + 1]; B2 = d4[nb + 2]; B3 = d4[nb + 3];
        GRP(A0, A1, A2, A3)
        int na = ((g + 2) & 255) << 2;               // wraps at end (unused load)
        A0 = d4[na]; A1 = d4[na + 1]; A2 = d4[na + 2]; A3 = d4[na + 3];
        GRP(B0, B1, B2, B3)
    }
    counts[(blockIdx.y << 16) + j] = (int)cnt;
}

// ------------- final: bracket search (noise-tolerant) + midpoint -------------
__global__ __launch_bounds__(256) void final_eig(const int* __restrict__ counts,
                                                 const unsigned* __restrict__ bu,
                                                 float* __restrict__ out) {
    int e = blockIdx.x * 256 + threadIdx.x;       // 8192 eigenvalues (l,k)
    int l = e >> 12, k = e & (RN - 1);
    const int* c = counts + (l << 16);
    int lo_i = 0, hi_i = G1 - 1;                  // last j with c[j] <= k
    while (lo_i < hi_i) {
        int mid = (lo_i + hi_i + 1) >> 1;
        if (c[mid] <= k) lo_i = mid; else hi_i = mid - 1;
    }
    while (lo_i > 0 && c[lo_i] > k) --lo_i;       // +-1 noise fixups
    while (lo_i < G1 - 1 && c[lo_i + 1] <= k) ++lo_i;
    float lo, cell;
    spect_bounds(bu, lo, cell);
    out[e] = lo + cell * ((float)lo_i + 0.5f);
}

extern "C" void kernel_launch(void* const* d_in, const int* in_sizes, int n_in,
                              void* d_out, int out_size, void* d_ws, size_t ws_size,
                              hipStream_t stream) {
    const float* energy = (const float*)d_in[0];
    const float* W1 = (const float*)d_in[1];
    const float* b1 = (const float*)d_in[2];
    const float* W2 = (const float*)d_in[3];
    const float* b2 = (const float*)d_in[4];
    const float* W3 = (const float*)d_in[5];
    const float* b3 = (const float*)d_in[6];
    float* out = (float*)d_out;                   // [RN] ptl, then [2*RN] eigenvalues

    float* ws = (float*)d_ws;
    float*    partA  = ws;                        // 131072 f32 (layers 1,3)
    float*    partB  = partA + 131072;            // 131072 f32 (layer 2)
    float*    D      = partB + 131072;            // 2*RN f32 (D0 | D1)
    unsigned* bu     = (unsigned*)(D + 2 * RN);   // 2 u32
    int*      counts = (int*)(bu + 4);            // 2*G1 i32 (512 KB)

    // ---- MLP: 3 GEMVs, fins fused into next layer's prologue ----
    part1 <<<dim3(8, 64),  256, 0, stream>>>(W1, energy, partA, bu);
    part2f<<<dim3(4, 128), 256, 0, stream>>>(W2, partA, b1, partB);
    part3f<<<dim3(16, 32), 256, 0, stream>>>(W3, partB, b2, partA);
    fin3  <<<RN / 256,     256, 0, stream>>>(partA, b3, out, D, bu);

    // ---- Eigenvalues: single-stage f32 Sturm multisection, 2 waves/SIMD ----
    stage1<<<dim3(G1 / 256, 2), 256, 0, stream>>>(D, bu, counts);
    final_eig<<<2 * RN / 256, 256, 0, stream>>>(counts, bu, out + RN);
}

// Round 8
// 75.401 us; speedup vs baseline: 1.4773x; 1.1563x over previous
//
#include <hip/hip_runtime.h>

#define CLIP 4096
#define H1   2048
#define H2   1024
#define RN   4096
#define H_STEP 2.44140625f   // r_i = H_STEP*(i+1) exactly
#define G1   65536           // Sturm grid points per l (131072 chains = 2 waves/SIMD)

// ---- monotone float<->uint map for atomic min/max of floats -----------------
__device__ __forceinline__ unsigned fmap(float f) {
    unsigned u = __float_as_uint(f);
    return (u & 0x80000000u) ? ~u : (u | 0x80000000u);
}
__device__ __forceinline__ float funmap(unsigned u) {
    return __uint_as_float((u & 0x80000000u) ? (u & 0x7fffffffu) : ~u);
}
__device__ __forceinline__ void spect_bounds(const unsigned* bu, float& lo, float& cell) {
    float mn = funmap(bu[0]), mx = funmap(bu[1]);
    lo = mn - 1e-3f;                              // Gershgorin: lambda_min >= min ptl
    float hi = mx + 2.33554432f + 1e-3f;          // lambda_max <= max ptl + 2 + 2/r0^2
    cell = (hi - lo) * (1.0f / (float)G1);
}

// ---------------- Layer 1 split-K partials: partA[c][j] ----------------------
__global__ __launch_bounds__(256) void part1(const float* __restrict__ W,
                                             const float* __restrict__ x,
                                             float* __restrict__ partA,
                                             unsigned* __restrict__ bu) {
    if (blockIdx.x == 0 && blockIdx.y == 0 && threadIdx.x == 0) {
        bu[0] = 0xFFFFFFFFu;   // running min (mapped)
        bu[1] = 0u;            // running max (mapped)
    }
    int j = blockIdx.x * 256 + threadIdx.x;       // 8 x-blocks -> j < 2048
    int i0 = blockIdx.y * 64;                     // 64 k-chunks of 64 rows
    const float* Wp = W + (size_t)i0 * H1 + j;
    float acc = 0.f;
#pragma unroll 8
    for (int i = 0; i < 64; ++i)
        acc = fmaf(x[i0 + i], Wp[(size_t)i * H1], acc);   // x uniform -> s_load
    partA[(size_t)blockIdx.y * H1 + j] = acc;
}

// ------- Layer 2, fused: prologue reduces the 16 h1 values this block needs --
__global__ __launch_bounds__(256) void part2f(const float* __restrict__ W,
                                              const float* __restrict__ partA,
                                              const float* __restrict__ b,
                                              float* __restrict__ partB) {
    __shared__ float xs[16];
    int t = threadIdx.x;
    int i_loc = t >> 4, c_loc = t & 15;           // 16 i's x 16 lanes
    int i0 = blockIdx.y * 16;                     // 128 k-chunks of 16 rows
    float s = 0.f;
#pragma unroll
    for (int k = 0; k < 4; ++k)                   // 64 layer-1 partials
        s += partA[(size_t)(c_loc + 16 * k) * H1 + i0 + i_loc];
    s += __shfl_xor(s, 1); s += __shfl_xor(s, 2);
    s += __shfl_xor(s, 4); s += __shfl_xor(s, 8);
    if (c_loc == 0) xs[i_loc] = fmaxf(s + b[i0 + i_loc], 0.f);
    __syncthreads();
    float xv[16];
#pragma unroll
    for (int u = 0; u < 16; ++u) xv[u] = xs[u];
    int j = blockIdx.x * 256 + t;                 // 4 x-blocks -> j < 1024
    const float* Wp = W + (size_t)i0 * H2 + j;
    float acc = 0.f;
#pragma unroll
    for (int i = 0; i < 16; ++i)
        acc = fmaf(xv[i], Wp[(size_t)i * H2], acc);
    partB[(size_t)blockIdx.y * H2 + j] = acc;
}

// ------- Layer 3, fused: prologue reduces the 32 h2 values this block needs --
__global__ __launch_bounds__(256) void part3f(const float* __restrict__ W,
                                              const float* __restrict__ partB,
                                              const float* __restrict__ b,
                                              float* __restrict__ partA) {
    __shared__ float xs[32];
    int t = threadIdx.x;
    int i_loc = t >> 3, c_loc = t & 7;            // 32 i's x 8 lanes
    int i0 = blockIdx.y * 32;                     // 32 k-chunks of 32 rows
    float s = 0.f;
#pragma unroll
    for (int k = 0; k < 16; ++k)                  // 128 layer-2 partials
        s += partB[(size_t)(c_loc + 8 * k) * H2 + i0 + i_loc];
    s += __shfl_xor(s, 1); s += __shfl_xor(s, 2); s += __shfl_xor(s, 4);
    if (c_loc == 0) xs[i_loc] = fmaxf(s + b[i0 + i_loc], 0.f);
    __syncthreads();
    float xv[32];
#pragma unroll
    for (int u = 0; u < 32; ++u) xv[u] = xs[u];
    int j = blockIdx.x * 256 + t;                 // 16 x-blocks -> j < 4096
    const float* Wp = W + (size_t)i0 * RN + j;
    float acc = 0.f;
#pragma unroll
    for (int i = 0; i < 32; ++i)
        acc = fmaf(xv[i], Wp[(size_t)i * RN], acc);
    partA[(size_t)blockIdx.y * RN + j] = acc;
}

// ---- Final fin: ptl -> d_out, D0/D1 = 2*diag (contiguous), spectral bounds --
__global__ __launch_bounds__(256) void fin3(const float* __restrict__ partA,
                                            const float* __restrict__ b,
                                            float* __restrict__ out,
                                            float* __restrict__ D,
                                            unsigned* __restrict__ bu) {
    __shared__ float smn[4], smx[4];
    int j = blockIdx.x * 256 + threadIdx.x;
    float s = b[j];
#pragma unroll 8
    for (int c = 0; c < 32; ++c) s += partA[(size_t)c * RN + j];
    out[j] = s;                                   // ptl -> d_out[0:RN]
    float r = H_STEP * (float)(j + 1);
    float base = 2.0f + 2.0f * s;                 // 2*(1 + ptl)
    D[j] = base;                                  // l = 0
    D[RN + j] = base + 4.0f / (r * r);            // l = 1: + 2*l(l+1)/r^2
    float mn = s, mx = s;
    for (int off = 32; off; off >>= 1) {
        mn = fminf(mn, __shfl_down(mn, off));
        mx = fmaxf(mx, __shfl_down(mx, off));
    }
    int tid = threadIdx.x;
    if ((tid & 63) == 0) { smn[tid >> 6] = mn; smx[tid >> 6] = mx; }
    __syncthreads();
    if (tid == 0) {
        for (int w = 1; w < 4; ++w) { mn = fminf(mn, smn[w]); mx = fmaxf(mx, smx[w]); }
        atomicMin(&bu[0], fmap(mn));
        atomicMax(&bu[1], fmap(mx));
    }
}

// -------- Sturm count, f32 char-poly recurrence  q_i = (D_i - X) q_{i-1} - q_{i-2}
// D = 2*diag, X = 2*x kills the 0.25 coefficient -> one fma per step.
// Per-step: v_sub + v_fma(neg) + v_alignbit (sign collector) = 3 VALU.
// Every 16 steps: popcount of adjacent-bit XOR (4 ops) + exponent renorm.
#define STEP(dv)                                                           \
    {                                                                      \
        float t = (dv) - X;                                                \
        float p = fmaf(t, pm1, -pm2);                                      \
        r = __builtin_amdgcn_alignbit(r, __float_as_uint(p), 31);          \
        pm2 = pm1; pm1 = p;                                                \
    }

// bits 0..15 of r: newest..oldest of this group's 16 signs; bit16: previous
// group's newest sign (carried automatically by the rolling register).
#define CNT16                                                              \
    {                                                                      \
        unsigned xx = (r ^ (r >> 1)) & 0xFFFFu;                            \
        cnt += (unsigned)__builtin_popcount(xx);                           \
    }

#define RENORM                                                             \
    {                                                                      \
        unsigned a1 = __float_as_uint(pm1) & 0x7fffffffu;                  \
        unsigned a2 = __float_as_uint(pm2) & 0x7fffffffu;                  \
        unsigned hm = a1 > a2 ? a1 : a2;                                   \
        int es = 254 - (int)(hm >> 23);                                    \
        es = es < 1 ? 1 : es;                                              \
        float sc = __uint_as_float((unsigned)es << 23);                    \
        pm1 *= sc; pm2 *= sc;                                              \
    }

__global__ __launch_bounds__(256) void stage1(const float* __restrict__ Dall,
                                              const unsigned* __restrict__ bu,
                                              int* __restrict__ counts) {
    __shared__ alignas(16) float ds[RN];
    const float* Dsrc = Dall + (blockIdx.y << 12);   // D0 | D1
    for (int i = threadIdx.x; i < RN / 4; i += 256)
        reinterpret_cast<float4*>(ds)[i] = reinterpret_cast<const float4*>(Dsrc)[i];
    __syncthreads();

    float lo, cell;
    spect_bounds(bu, lo, cell);
    int j = blockIdx.x * 256 + threadIdx.x;          // 256 x-blocks -> j < 65536
    float X = 2.0f * (lo + cell * (float)j);

    float pm1 = 1.0f, pm2 = 0.0f;
    unsigned cnt = 0, r = 0;                         // r bit0 = sign(p_0) = +
    const float4* d4 = reinterpret_cast<const float4*>(ds);

    // 32 outer iters x 128-step unrolled body; all ds_read offsets are
    // compile-time immediates off one per-iter base (no dynamic addressing).
    for (int w = 0; w < 32; ++w) {
        const float4* g = d4 + w * 32;               // 32 float4 = 128 steps
#pragma unroll
        for (int q = 0; q < 8; ++q) {                // 8 groups of 16 steps
            float4 a = g[q * 4 + 0];
            float4 b2 = g[q * 4 + 1];
            float4 c2 = g[q * 4 + 2];
            float4 e2 = g[q * 4 + 3];
            STEP(a.x)  STEP(a.y)  STEP(a.z)  STEP(a.w)
            STEP(b2.x) STEP(b2.y) STEP(b2.z) STEP(b2.w)
            STEP(c2.x) STEP(c2.y) STEP(c2.z) STEP(c2.w)
            STEP(e2.x) STEP(e2.y) STEP(e2.z) STEP(e2.w)
            CNT16
            RENORM
        }
    }
    counts[(blockIdx.y << 16) + j] = (int)cnt;
}

// ------------- final: bracket search (noise-tolerant) + midpoint -------------
__global__ __launch_bounds__(256) void final_eig(const int* __restrict__ counts,
                                                 const unsigned* __restrict__ bu,
                                                 float* __restrict__ out) {
    int e = blockIdx.x * 256 + threadIdx.x;       // 8192 eigenvalues (l,k)
    int l = e >> 12, k = e & (RN - 1);
    const int* c = counts + (l << 16);
    int lo_i = 0, hi_i = G1 - 1;                  // last j with c[j] <= k
    while (lo_i < hi_i) {
        int mid = (lo_i + hi_i + 1) >> 1;
        if (c[mid] <= k) lo_i = mid; else hi_i = mid - 1;
    }
    while (lo_i > 0 && c[lo_i] > k) --lo_i;       // +-1 noise fixups
    while (lo_i < G1 - 1 && c[lo_i + 1] <= k) ++lo_i;
    float lo, cell;
    spect_bounds(bu, lo, cell);
    out[e] = lo + cell * ((float)lo_i + 0.5f);
}

extern "C" void kernel_launch(void* const* d_in, const int* in_sizes, int n_in,
                              void* d_out, int out_size, void* d_ws, size_t ws_size,
                              hipStream_t stream) {
    const float* energy = (const float*)d_in[0];
    const float* W1 = (const float*)d_in[1];
    const float* b1 = (const float*)d_in[2];
    const float* W2 = (const float*)d_in[3];
    const float* b2 = (const float*)d_in[4];
    const float* W3 = (const float*)d_in[5];
    const float* b3 = (const float*)d_in[6];
    float* out = (float*)d_out;                   // [RN] ptl, then [2*RN] eigenvalues

    float* ws = (float*)d_ws;
    float*    partA  = ws;                        // 131072 f32 (layers 1,3)
    float*    partB  = partA + 131072;            // 131072 f32 (layer 2)
    float*    D      = partB + 131072;            // 2*RN f32 (D0 | D1)
    unsigned* bu     = (unsigned*)(D + 2 * RN);   // 2 u32
    int*      counts = (int*)(bu + 4);            // 2*G1 i32 (512 KB)

    // ---- MLP: 3 GEMVs, fins fused into next layer's prologue ----
    part1 <<<dim3(8, 64),  256, 0, stream>>>(W1, energy, partA, bu);
    part2f<<<dim3(4, 128), 256, 0, stream>>>(W2, partA, b1, partB);
    part3f<<<dim3(16, 32), 256, 0, stream>>>(W3, partB, b2, partA);
    fin3  <<<RN / 256,     256, 0, stream>>>(partA, b3, out, D, bu);

    // ---- Eigenvalues: single-stage f32 Sturm multisection, 2 waves/SIMD ----
    stage1<<<dim3(G1 / 256, 2), 256, 0, stream>>>(D, bu, counts);
    final_eig<<<2 * RN / 256, 256, 0, stream>>>(counts, bu, out + RN);
}